// Round 2
// baseline (5946.031 us; speedup 1.0000x reference)
//
#include <hip/hip_runtime.h>
#include <cstdint>
#include <cstddef>

#define NN 50000
#define EE 300000
#define HH 64
#define PP 3
#define GG 50
#define LL 2
#define SLOPE 0.01f

__device__ __forceinline__ float lrelu(float x){ return x >= 0.f ? x : SLOPE*x; }

// gstart[g] = first index i with batch[i] >= g (batch sorted); gstart[GG] = NN
__global__ void k_bounds(const int* __restrict__ batch, int* __restrict__ gstart){
    int g = threadIdx.x;
    if (g > GG) return;
    int lo = 0, hi = NN;
    while (lo < hi){ int mid = (lo + hi) >> 1; if (batch[mid] < g) lo = mid + 1; else hi = mid; }
    gstart[g] = lo;
}

// deg[which][n] = sum of w over edges with row==n; which in 0..5 (u hops 0..2, f hops 0..2)
__global__ void k_deg(const int* __restrict__ uei, const float* __restrict__ uew,
                      const int* __restrict__ fei, const float* __restrict__ few,
                      float* __restrict__ deg){
    int t = blockIdx.x * blockDim.x + threadIdx.x;
    if (t >= 2 * PP * EE) return;
    int which = t / EE;
    int e = t - which * EE;
    const int* ei; const float* ew; int p;
    if (which < PP){ ei = uei; ew = uew; p = which; }
    else           { ei = fei; ew = few; p = which - PP; }
    int row = ei[(size_t)(p * 2 + 0) * EE + e];
    atomicAdd(deg + (size_t)which * NN + row, ew[(size_t)p * EE + e]);
}

// out[n,o] = sum_k X[n,k] * W[k,o] + b[o]   (K = 64)
__global__ void k_mm64(const float* __restrict__ X, const float* __restrict__ W,
                       const float* __restrict__ b, float* __restrict__ out){
    int gid = blockIdx.x * blockDim.x + threadIdx.x;
    if (gid >= NN * HH) return;
    int n = gid >> 6, o = gid & 63;
    const float* xr = X + (size_t)n * HH;
    float acc = b[o];
    #pragma unroll
    for (int k = 0; k < HH; ++k) acc += xr[k] * W[k * HH + o];
    out[gid] = acc;
}

// Y[n, s, o], s in 0..7:
//   s<6 : sum_h xt[n,h] * fW[(128 + h*6 + s)*64 + o]   (directional slice T_s)
//   s==6: sum_h xt[n,h] * fW[(64 + h)*64 + o]          (avg slice)
//   s==7: sum_h xt[n,h] * fW[h*64 + o]                 (self slice)
__global__ void k_ybuild(const float* __restrict__ xt, const float* __restrict__ fW,
                         float* __restrict__ Y){
    int gid = blockIdx.x * blockDim.x + threadIdx.x;
    if (gid >= NN * 512) return;
    int n = gid >> 9;
    int so = gid & 511;
    int s = so >> 6, o = so & 63;
    const float* xr = xt + (size_t)n * HH;
    float acc = 0.f;
    if (s < 6){
        #pragma unroll
        for (int h = 0; h < HH; ++h) acc += xr[h] * fW[(128 + h * 6 + s) * HH + o];
    } else if (s == 6){
        #pragma unroll
        for (int h = 0; h < HH; ++h) acc += xr[h] * fW[(64 + h) * HH + o];
    } else {
        #pragma unroll
        for (int h = 0; h < HH; ++h) acc += xr[h] * fW[h * HH + o];
    }
    Y[gid] = acc;
}

// per edge: msg[o] = w*Y[col,6,o] + sum_d |diff_d| * Y[col, d + 3*(diff_d<0), o]; atomic into acc[row]
__global__ void k_edge(const int* __restrict__ rowi, const int* __restrict__ coli,
                       const float* __restrict__ w, const float* __restrict__ pe,
                       const float* __restrict__ Y, float* __restrict__ acc){
    int gid = blockIdx.x * blockDim.x + threadIdx.x;
    if (gid >= EE * HH) return;
    int e = gid >> 6, o = gid & 63;
    int row = rowi[e], col = coli[e];
    float we = w[e];
    float dr0 = pe[col * 3 + 0] - pe[row * 3 + 0];
    float dr1 = pe[col * 3 + 1] - pe[row * 3 + 1];
    float dr2 = pe[col * 3 + 2] - pe[row * 3 + 2];
    const float* Yc = Y + (size_t)col * 512;
    float m = we * Yc[6 * 64 + o];
    int s0 = (dr0 < 0.f) ? 3 : 0; m += fabsf(dr0) * Yc[s0 * 64 + o];
    int s1 = (dr1 < 0.f) ? 4 : 1; m += fabsf(dr1) * Yc[s1 * 64 + o];
    int s2 = (dr2 < 0.f) ? 5 : 2; m += fabsf(dr2) * Yc[s2 * 64 + o];
    atomicAdd(acc + (size_t)row * 64 + o, m);
}

// hop finalize: h_p = lrelu(Y[n,7,o] + deg_inv*acc + fb); out (+)= h_p * softmax_p(d)[p,o] + hb[o]
__global__ void k_fin(const float* __restrict__ Y, const float* __restrict__ acc,
                      const float* __restrict__ deg, const float* __restrict__ fb,
                      const float* __restrict__ dmat, const float* __restrict__ hb,
                      int p, int first, float* __restrict__ out){
    int gid = blockIdx.x * blockDim.x + threadIdx.x;
    if (gid >= NN * HH) return;
    int n = gid >> 6, o = gid & 63;
    float dg = deg[n];
    float di = (dg == 0.f) ? 0.f : 1.f / dg;
    float hpre = Y[(size_t)n * 512 + 448 + o] + di * acc[gid] + fb[o];
    float hp = lrelu(hpre);
    float d0 = dmat[0 * HH + o], d1 = dmat[1 * HH + o], d2 = dmat[2 * HH + o];
    float mx = fmaxf(d0, fmaxf(d1, d2));
    float e0 = expf(d0 - mx), e1 = expf(d1 - mx), e2 = expf(d2 - mx);
    float dw = ((p == 0) ? e0 : (p == 1) ? e1 : e2) / (e0 + e1 + e2);
    float v = hp * dw + hb[o];
    out[gid] = first ? v : (out[gid] + v);
}

// per-graph column sums and sum-of-squares (writes, no accumulation)
__global__ void k_stats(const float* __restrict__ X, const int* __restrict__ gstart,
                        float* __restrict__ sums, float* __restrict__ sumsq){
    int g = blockIdx.x;
    int tid = threadIdx.x;          // 1024 threads = 16 subs x 64 cols
    int o = tid & 63, sub = tid >> 6;
    int ns = gstart[g], ne = gstart[g + 1];
    float s = 0.f, q = 0.f;
    for (int n = ns + sub; n < ne; n += 16){
        float v = X[(size_t)n * 64 + o];
        s += v; q += v * v;
    }
    __shared__ float ls[16][64];
    __shared__ float lq[16][64];
    ls[sub][o] = s; lq[sub][o] = q;
    __syncthreads();
    if (sub == 0){
        #pragma unroll
        for (int k = 1; k < 16; ++k){ s += ls[k][o]; q += lq[k][o]; }
        sums[g * 64 + o] = s;
        sumsq[g * 64 + o] = q;
    }
}

// graph-norm + leaky_relu, in place.  var = E[x^2] - mean^2 * ms * (2 - ms)
__global__ void k_gnorm(float* __restrict__ X, const int* __restrict__ batch,
                        const int* __restrict__ gstart,
                        const float* __restrict__ sums, const float* __restrict__ sumsq,
                        const float* __restrict__ w, const float* __restrict__ b,
                        const float* __restrict__ ms){
    int gid = blockIdx.x * blockDim.x + threadIdx.x;
    if (gid >= NN * HH) return;
    int n = gid >> 6, o = gid & 63;
    int g = batch[n];
    float cnt = fmaxf((float)(gstart[g + 1] - gstart[g]), 1.f);
    float mean = sums[g * 64 + o] / cnt;
    float ex2 = sumsq[g * 64 + o] / cnt;
    float m = ms[o];
    float var = ex2 - mean * mean * m * (2.f - m);
    float v = (X[gid] - mean * m) * (1.f / sqrtf(var + 1e-5f)) * w[o] + b[o];
    X[gid] = lrelu(v);
}

// gate = sigmoid([h,fx] @ gate_W + gate_b); X = gate*h + (1-gate)*fx + X
__global__ void k_gate(const float* __restrict__ h, const float* __restrict__ fx,
                       const float* __restrict__ gW, const float* __restrict__ gb,
                       float* __restrict__ X){
    int gid = blockIdx.x * blockDim.x + threadIdx.x;
    if (gid >= NN * HH) return;
    int n = gid >> 6, o = gid & 63;
    const float* hr = h + (size_t)n * HH;
    const float* fr = fx + (size_t)n * HH;
    float acc = gb[o];
    #pragma unroll
    for (int k = 0; k < HH; ++k) acc += hr[k] * gW[k * HH + o];
    #pragma unroll
    for (int k = 0; k < HH; ++k) acc += fr[k] * gW[(64 + k) * HH + o];
    float gt = 1.f / (1.f + expf(-acc));
    X[gid] = gt * hr[o] + (1.f - gt) * fr[o] + X[gid];
}

__global__ void k_finalout(const float* __restrict__ sums, const int* __restrict__ gstart,
                           float* __restrict__ out){
    int gid = blockIdx.x * blockDim.x + threadIdx.x;
    if (gid >= GG * HH) return;
    int g = gid >> 6;
    float cnt = fmaxf((float)(gstart[g + 1] - gstart[g]), 1.f);
    out[gid] = sums[gid] / cnt;
}

extern "C" void kernel_launch(void* const* d_in, const int* in_sizes, int n_in,
                              void* d_out, int out_size, void* d_ws, size_t ws_size,
                              hipStream_t stream) {
    const float* x_in   = (const float*)d_in[0];
    const float* pe     = (const float*)d_in[1];
    const int*   batch  = (const int*)d_in[2];
    const int*   uei    = (const int*)d_in[3];
    const float* uew    = (const float*)d_in[4];
    const int*   fei    = (const int*)d_in[5];
    const float* few    = (const float*)d_in[6];
    const float* emb_W  = (const float*)d_in[7];
    const float* emb_b  = (const float*)d_in[8];
    const float* S_lin_W= (const float*)d_in[9];
    const float* S_lin_b= (const float*)d_in[10];
    const float* S_d    = (const float*)d_in[11];
    const float* S_hb   = (const float*)d_in[12];
    const float* S_fW   = (const float*)d_in[13];
    const float* S_fb   = (const float*)d_in[14];
    const float* F_lin_W= (const float*)d_in[15];
    const float* F_lin_b= (const float*)d_in[16];
    const float* F_d    = (const float*)d_in[17];
    const float* F_hb   = (const float*)d_in[18];
    const float* F_fW   = (const float*)d_in[19];
    const float* F_fb   = (const float*)d_in[20];
    const float* nS_w   = (const float*)d_in[21];
    const float* nS_b   = (const float*)d_in[22];
    const float* nS_m   = (const float*)d_in[23];
    const float* nF_w   = (const float*)d_in[24];
    const float* nF_b   = (const float*)d_in[25];
    const float* nF_m   = (const float*)d_in[26];
    const float* gate_W = (const float*)d_in[27];
    const float* gate_b = (const float*)d_in[28];
    float* out = (float*)d_out;

    size_t off = 0;
    auto alloc = [&](size_t bytes)->void*{
        void* p = (char*)d_ws + off;
        off += (bytes + 255) & ~(size_t)255;
        return p;
    };
    float* xbuf  = (float*)alloc((size_t)NN * HH * 4);
    float* hbuf  = (float*)alloc((size_t)NN * HH * 4);
    float* fxbuf = (float*)alloc((size_t)NN * HH * 4);
    float* xt    = (float*)alloc((size_t)NN * HH * 4);
    float* accb  = (float*)alloc((size_t)NN * HH * 4);
    float* Y     = (float*)alloc((size_t)NN * 512 * 4);
    float* deg   = (float*)alloc((size_t)6 * NN * 4);
    int*   gstart= (int*)  alloc((GG + 1) * 4);
    float* sums  = (float*)alloc(GG * HH * 4);
    float* sumsq = (float*)alloc(GG * HH * 4);

    const int BLK = 256;
    const int gridNH = (NN * HH) / BLK;          // 12500
    const int gridY  = (NN * 512) / BLK;         // 100000
    const int gridE  = (EE * HH) / BLK;          // 75000

    k_bounds<<<1, 64, 0, stream>>>(batch, gstart);
    hipMemsetAsync(deg, 0, (size_t)6 * NN * 4, stream);
    k_deg<<<(2 * PP * EE + BLK - 1) / BLK, BLK, 0, stream>>>(uei, uew, fei, few, deg);
    k_mm64<<<gridNH, BLK, 0, stream>>>(x_in, emb_W, emb_b, xbuf);

    auto opdmp = [&](const float* xin, float* outb, const int* ei, const float* ew,
                     const float* degset, const float* linW, const float* linb,
                     const float* dmat, const float* hbias, const float* fW, const float* fb){
        k_mm64<<<gridNH, BLK, 0, stream>>>(xin, linW, linb, xt);
        for (int p = 0; p < PP; ++p){
            k_ybuild<<<gridY, BLK, 0, stream>>>(xt, fW + (size_t)p * 512 * HH, Y);
            hipMemsetAsync(accb, 0, (size_t)NN * HH * 4, stream);
            k_edge<<<gridE, BLK, 0, stream>>>(ei + (size_t)(p * 2 + 0) * EE,
                                              ei + (size_t)(p * 2 + 1) * EE,
                                              ew + (size_t)p * EE, pe, Y, accb);
            k_fin<<<gridNH, BLK, 0, stream>>>(Y, accb, degset + (size_t)p * NN,
                                              fb + p * HH, dmat,
                                              hbias + p * HH, p, (p == 0) ? 1 : 0, outb);
        }
    };
    auto gnorm = [&](float* X, const float* w, const float* b, const float* ms){
        k_stats<<<GG, 1024, 0, stream>>>(X, gstart, sums, sumsq);
        k_gnorm<<<gridNH, BLK, 0, stream>>>(X, batch, gstart, sums, sumsq, w, b, ms);
    };

    for (int i = 0; i < LL; ++i){
        opdmp(xbuf, hbuf, uei, uew, deg,
              S_lin_W + (size_t)i * HH * HH, S_lin_b + (size_t)i * HH,
              S_d + (size_t)i * PP * HH, S_hb + (size_t)i * PP * HH,
              S_fW + (size_t)i * PP * 512 * HH, S_fb + (size_t)i * PP * HH);
        gnorm(hbuf, nS_w + (size_t)i * HH, nS_b + (size_t)i * HH, nS_m + (size_t)i * HH);
        opdmp(hbuf, fxbuf, fei, few, deg + (size_t)PP * NN,
              F_lin_W + (size_t)i * HH * HH, F_lin_b + (size_t)i * HH,
              F_d + (size_t)i * PP * HH, F_hb + (size_t)i * PP * HH,
              F_fW + (size_t)i * PP * 512 * HH, F_fb + (size_t)i * PP * HH);
        gnorm(fxbuf, nF_w + (size_t)i * HH, nF_b + (size_t)i * HH, nF_m + (size_t)i * HH);
        k_gate<<<gridNH, BLK, 0, stream>>>(hbuf, fxbuf, gate_W, gate_b, xbuf);
    }

    k_stats<<<GG, 1024, 0, stream>>>(xbuf, gstart, sums, sumsq);
    k_finalout<<<(GG * HH + BLK - 1) / BLK, BLK, 0, stream>>>(sums, gstart, out);
}

// Round 3
// 2471.651 us; speedup vs baseline: 2.4057x; 2.4057x over previous
//
#include <hip/hip_runtime.h>
#include <cstdint>
#include <cstddef>

#define NN 50000
#define EE 300000
#define HH 64
#define PP 3
#define GG 50
#define LL 2
#define SLOPE 0.01f

__device__ __forceinline__ float lrelu(float x){ return x >= 0.f ? x : SLOPE*x; }

// gstart[g] = first index i with batch[i] >= g (batch sorted); gstart[GG] = NN
__global__ void k_bounds(const int* __restrict__ batch, int* __restrict__ gstart){
    int g = threadIdx.x;
    if (g > GG) return;
    int lo = 0, hi = NN;
    while (lo < hi){ int mid = (lo + hi) >> 1; if (batch[mid] < g) lo = mid + 1; else hi = mid; }
    gstart[g] = lo;
}

// deg[which][n] = sum of w over edges with row==n; which in 0..5 (u hops 0..2, f hops 0..2)
__global__ void k_deg(const int* __restrict__ uei, const float* __restrict__ uew,
                      const int* __restrict__ fei, const float* __restrict__ few,
                      float* __restrict__ deg){
    int t = blockIdx.x * blockDim.x + threadIdx.x;
    if (t >= 2 * PP * EE) return;
    int which = t / EE;
    int e = t - which * EE;
    const int* ei; const float* ew; int p;
    if (which < PP){ ei = uei; ew = uew; p = which; }
    else           { ei = fei; ew = few; p = which - PP; }
    int row = ei[(size_t)(p * 2 + 0) * EE + e];
    atomicAdd(deg + (size_t)which * NN + row, ew[(size_t)p * EE + e]);
}

// Register-blocked (N,64)@(64,64): each wave handles 16 nodes, lane owns 1 column.
__global__ __launch_bounds__(256) void k_lin64(const float* __restrict__ X,
                       const float* __restrict__ W, const float* __restrict__ b,
                       float* __restrict__ out){
    __shared__ float xs[64][HH];
    int nb = blockIdx.x * 64;
    int t = threadIdx.x;
    #pragma unroll
    for (int i = 0; i < 4; ++i){
        int idx = t + 256 * i;
        int r = idx >> 4, c4 = idx & 15;
        int n = nb + r;
        float4 v = make_float4(0.f, 0.f, 0.f, 0.f);
        if (n < NN) v = *reinterpret_cast<const float4*>(X + (size_t)n * HH + c4 * 4);
        *reinterpret_cast<float4*>(&xs[r][c4 * 4]) = v;
    }
    __syncthreads();
    int lane = t & 63, wave = t >> 6, nw = wave * 16;
    float acc[16];
    float bb = b[lane];
    #pragma unroll
    for (int i = 0; i < 16; ++i) acc[i] = bb;
    for (int k = 0; k < HH; ++k){
        float wv = W[(size_t)k * HH + lane];
        #pragma unroll
        for (int i = 0; i < 16; ++i) acc[i] += xs[nw + i][k] * wv;
    }
    #pragma unroll
    for (int i = 0; i < 16; ++i){
        int n = nb + nw + i;
        if (n < NN) out[(size_t)n * HH + lane] = acc[i];
    }
}

// Y[n, s, o], s in 0..7 (6 directional, avg, self), register-blocked GEMM.
// Each wave: 16 nodes; lane owns column `lane` of all 8 slices -> acc[16][8].
__global__ __launch_bounds__(256) void k_ybuild2(const float* __restrict__ xt,
                        const float* __restrict__ fW, float* __restrict__ Y){
    __shared__ float xs[64][HH];
    int nb = blockIdx.x * 64;
    int t = threadIdx.x;
    #pragma unroll
    for (int i = 0; i < 4; ++i){
        int idx = t + 256 * i;
        int r = idx >> 4, c4 = idx & 15;
        int n = nb + r;
        float4 v = make_float4(0.f, 0.f, 0.f, 0.f);
        if (n < NN) v = *reinterpret_cast<const float4*>(xt + (size_t)n * HH + c4 * 4);
        *reinterpret_cast<float4*>(&xs[r][c4 * 4]) = v;
    }
    __syncthreads();
    int lane = t & 63, wave = t >> 6, nw = wave * 16;
    float acc[16][8];
    #pragma unroll
    for (int i = 0; i < 16; ++i)
        #pragma unroll
        for (int j = 0; j < 8; ++j) acc[i][j] = 0.f;
    for (int k = 0; k < HH; ++k){
        float wv[8];
        #pragma unroll
        for (int j = 0; j < 6; ++j) wv[j] = fW[(size_t)(128 + k * 6 + j) * HH + lane];
        wv[6] = fW[(size_t)(64 + k) * HH + lane];
        wv[7] = fW[(size_t)k * HH + lane];
        #pragma unroll
        for (int i = 0; i < 16; ++i){
            float xv = xs[nw + i][k];
            #pragma unroll
            for (int j = 0; j < 8; ++j) acc[i][j] += xv * wv[j];
        }
    }
    #pragma unroll
    for (int i = 0; i < 16; ++i){
        int n = nb + nw + i;
        if (n < NN){
            float* yr = Y + (size_t)n * 512 + lane;
            #pragma unroll
            for (int j = 0; j < 8; ++j) yr[j * 64] = acc[i][j];
        }
    }
}

// per edge: msg[o] = w*Y[col,6,o] + sum_d |diff_d| * Y[col, d + 3*(diff_d<0), o]; atomic into acc[row]
__global__ void k_edge(const int* __restrict__ rowi, const int* __restrict__ coli,
                       const float* __restrict__ w, const float* __restrict__ pe,
                       const float* __restrict__ Y, float* __restrict__ acc){
    int gid = blockIdx.x * blockDim.x + threadIdx.x;
    if (gid >= EE * HH) return;
    int e = gid >> 6, o = gid & 63;
    int row = rowi[e], col = coli[e];
    float we = w[e];
    float dr0 = pe[col * 3 + 0] - pe[row * 3 + 0];
    float dr1 = pe[col * 3 + 1] - pe[row * 3 + 1];
    float dr2 = pe[col * 3 + 2] - pe[row * 3 + 2];
    const float* Yc = Y + (size_t)col * 512;
    float m = we * Yc[6 * 64 + o];
    int s0 = (dr0 < 0.f) ? 3 : 0; m += fabsf(dr0) * Yc[s0 * 64 + o];
    int s1 = (dr1 < 0.f) ? 4 : 1; m += fabsf(dr1) * Yc[s1 * 64 + o];
    int s2 = (dr2 < 0.f) ? 5 : 2; m += fabsf(dr2) * Yc[s2 * 64 + o];
    atomicAdd(acc + (size_t)row * 64 + o, m);
}

// hop finalize: h_p = lrelu(Y[n,7,o] + deg_inv*acc + fb); out (+)= h_p * softmax_p(d)[p,o] + hb[o]
__global__ void k_fin(const float* __restrict__ Y, const float* __restrict__ acc,
                      const float* __restrict__ deg, const float* __restrict__ fb,
                      const float* __restrict__ dmat, const float* __restrict__ hb,
                      int p, int first, float* __restrict__ out){
    int gid = blockIdx.x * blockDim.x + threadIdx.x;
    if (gid >= NN * HH) return;
    int n = gid >> 6, o = gid & 63;
    float dg = deg[n];
    float di = (dg == 0.f) ? 0.f : 1.f / dg;
    float hpre = Y[(size_t)n * 512 + 448 + o] + di * acc[gid] + fb[o];
    float hp = lrelu(hpre);
    float d0 = dmat[0 * HH + o], d1 = dmat[1 * HH + o], d2 = dmat[2 * HH + o];
    float mx = fmaxf(d0, fmaxf(d1, d2));
    float e0 = expf(d0 - mx), e1 = expf(d1 - mx), e2 = expf(d2 - mx);
    float dw = ((p == 0) ? e0 : (p == 1) ? e1 : e2) / (e0 + e1 + e2);
    float v = hp * dw + hb[o];
    out[gid] = first ? v : (out[gid] + v);
}

// per-graph column sums and sum-of-squares (writes, no accumulation)
__global__ void k_stats(const float* __restrict__ X, const int* __restrict__ gstart,
                        float* __restrict__ sums, float* __restrict__ sumsq){
    int g = blockIdx.x;
    int tid = threadIdx.x;          // 1024 threads = 16 subs x 64 cols
    int o = tid & 63, sub = tid >> 6;
    int ns = gstart[g], ne = gstart[g + 1];
    float s = 0.f, q = 0.f;
    for (int n = ns + sub; n < ne; n += 16){
        float v = X[(size_t)n * 64 + o];
        s += v; q += v * v;
    }
    __shared__ float ls[16][64];
    __shared__ float lq[16][64];
    ls[sub][o] = s; lq[sub][o] = q;
    __syncthreads();
    if (sub == 0){
        #pragma unroll
        for (int k = 1; k < 16; ++k){ s += ls[k][o]; q += lq[k][o]; }
        sums[g * 64 + o] = s;
        sumsq[g * 64 + o] = q;
    }
}

// graph-norm + leaky_relu, in place.  var = E[x^2] - mean^2 * ms * (2 - ms)
__global__ void k_gnorm(float* __restrict__ X, const int* __restrict__ batch,
                        const int* __restrict__ gstart,
                        const float* __restrict__ sums, const float* __restrict__ sumsq,
                        const float* __restrict__ w, const float* __restrict__ b,
                        const float* __restrict__ ms){
    int gid = blockIdx.x * blockDim.x + threadIdx.x;
    if (gid >= NN * HH) return;
    int n = gid >> 6, o = gid & 63;
    int g = batch[n];
    float cnt = fmaxf((float)(gstart[g + 1] - gstart[g]), 1.f);
    float mean = sums[g * 64 + o] / cnt;
    float ex2 = sumsq[g * 64 + o] / cnt;
    float m = ms[o];
    float var = ex2 - mean * mean * m * (2.f - m);
    float v = (X[gid] - mean * m) * (1.f / sqrtf(var + 1e-5f)) * w[o] + b[o];
    X[gid] = lrelu(v);
}

// gate = sigmoid([h,fx] @ gate_W + gate_b); X = gate*h + (1-gate)*fx + X
// Register-blocked like k_lin64, two staged tiles.
__global__ __launch_bounds__(256) void k_gate2(const float* __restrict__ h,
                       const float* __restrict__ fx, const float* __restrict__ gW,
                       const float* __restrict__ gb, float* __restrict__ X){
    __shared__ float hs[64][HH];
    __shared__ float fs[64][HH];
    int nb = blockIdx.x * 64;
    int t = threadIdx.x;
    #pragma unroll
    for (int i = 0; i < 4; ++i){
        int idx = t + 256 * i;
        int r = idx >> 4, c4 = idx & 15;
        int n = nb + r;
        float4 vh = make_float4(0.f, 0.f, 0.f, 0.f);
        float4 vf = make_float4(0.f, 0.f, 0.f, 0.f);
        if (n < NN){
            vh = *reinterpret_cast<const float4*>(h  + (size_t)n * HH + c4 * 4);
            vf = *reinterpret_cast<const float4*>(fx + (size_t)n * HH + c4 * 4);
        }
        *reinterpret_cast<float4*>(&hs[r][c4 * 4]) = vh;
        *reinterpret_cast<float4*>(&fs[r][c4 * 4]) = vf;
    }
    __syncthreads();
    int lane = t & 63, wave = t >> 6, nw = wave * 16;
    float acc[16];
    float bb = gb[lane];
    #pragma unroll
    for (int i = 0; i < 16; ++i) acc[i] = bb;
    for (int k = 0; k < HH; ++k){
        float w1 = gW[(size_t)k * HH + lane];
        float w2 = gW[(size_t)(64 + k) * HH + lane];
        #pragma unroll
        for (int i = 0; i < 16; ++i) acc[i] += hs[nw + i][k] * w1 + fs[nw + i][k] * w2;
    }
    #pragma unroll
    for (int i = 0; i < 16; ++i){
        int n = nb + nw + i;
        if (n < NN){
            float gt = 1.f / (1.f + expf(-acc[i]));
            float hv = hs[nw + i][lane];
            float fv = fs[nw + i][lane];
            size_t idx = (size_t)n * HH + lane;
            X[idx] = gt * hv + (1.f - gt) * fv + X[idx];
        }
    }
}

__global__ void k_finalout(const float* __restrict__ sums, const int* __restrict__ gstart,
                           float* __restrict__ out){
    int gid = blockIdx.x * blockDim.x + threadIdx.x;
    if (gid >= GG * HH) return;
    int g = gid >> 6;
    float cnt = fmaxf((float)(gstart[g + 1] - gstart[g]), 1.f);
    out[gid] = sums[gid] / cnt;
}

extern "C" void kernel_launch(void* const* d_in, const int* in_sizes, int n_in,
                              void* d_out, int out_size, void* d_ws, size_t ws_size,
                              hipStream_t stream) {
    const float* x_in   = (const float*)d_in[0];
    const float* pe     = (const float*)d_in[1];
    const int*   batch  = (const int*)d_in[2];
    const int*   uei    = (const int*)d_in[3];
    const float* uew    = (const float*)d_in[4];
    const int*   fei    = (const int*)d_in[5];
    const float* few    = (const float*)d_in[6];
    const float* emb_W  = (const float*)d_in[7];
    const float* emb_b  = (const float*)d_in[8];
    const float* S_lin_W= (const float*)d_in[9];
    const float* S_lin_b= (const float*)d_in[10];
    const float* S_d    = (const float*)d_in[11];
    const float* S_hb   = (const float*)d_in[12];
    const float* S_fW   = (const float*)d_in[13];
    const float* S_fb   = (const float*)d_in[14];
    const float* F_lin_W= (const float*)d_in[15];
    const float* F_lin_b= (const float*)d_in[16];
    const float* F_d    = (const float*)d_in[17];
    const float* F_hb   = (const float*)d_in[18];
    const float* F_fW   = (const float*)d_in[19];
    const float* F_fb   = (const float*)d_in[20];
    const float* nS_w   = (const float*)d_in[21];
    const float* nS_b   = (const float*)d_in[22];
    const float* nS_m   = (const float*)d_in[23];
    const float* nF_w   = (const float*)d_in[24];
    const float* nF_b   = (const float*)d_in[25];
    const float* nF_m   = (const float*)d_in[26];
    const float* gate_W = (const float*)d_in[27];
    const float* gate_b = (const float*)d_in[28];
    float* out = (float*)d_out;

    size_t off = 0;
    auto alloc = [&](size_t bytes)->void*{
        void* p = (char*)d_ws + off;
        off += (bytes + 255) & ~(size_t)255;
        return p;
    };
    float* xbuf  = (float*)alloc((size_t)NN * HH * 4);
    float* hbuf  = (float*)alloc((size_t)NN * HH * 4);
    float* fxbuf = (float*)alloc((size_t)NN * HH * 4);
    float* xt    = (float*)alloc((size_t)NN * HH * 4);
    float* accb  = (float*)alloc((size_t)NN * HH * 4);
    float* Y     = (float*)alloc((size_t)NN * 512 * 4);
    float* deg   = (float*)alloc((size_t)6 * NN * 4);
    int*   gstart= (int*)  alloc((GG + 1) * 4);
    float* sums  = (float*)alloc(GG * HH * 4);
    float* sumsq = (float*)alloc(GG * HH * 4);

    const int BLK = 256;
    const int gridNH = (NN * HH) / BLK;          // 12500
    const int gridE  = (EE * HH) / BLK;          // 75000
    const int gridN64 = (NN + 63) / 64;          // 782

    k_bounds<<<1, 64, 0, stream>>>(batch, gstart);
    hipMemsetAsync(deg, 0, (size_t)6 * NN * 4, stream);
    k_deg<<<(2 * PP * EE + BLK - 1) / BLK, BLK, 0, stream>>>(uei, uew, fei, few, deg);
    k_lin64<<<gridN64, BLK, 0, stream>>>(x_in, emb_W, emb_b, xbuf);

    auto opdmp = [&](const float* xin, float* outb, const int* ei, const float* ew,
                     const float* degset, const float* linW, const float* linb,
                     const float* dmat, const float* hbias, const float* fW, const float* fb){
        k_lin64<<<gridN64, BLK, 0, stream>>>(xin, linW, linb, xt);
        for (int p = 0; p < PP; ++p){
            k_ybuild2<<<gridN64, BLK, 0, stream>>>(xt, fW + (size_t)p * 512 * HH, Y);
            hipMemsetAsync(accb, 0, (size_t)NN * HH * 4, stream);
            k_edge<<<gridE, BLK, 0, stream>>>(ei + (size_t)(p * 2 + 0) * EE,
                                              ei + (size_t)(p * 2 + 1) * EE,
                                              ew + (size_t)p * EE, pe, Y, accb);
            k_fin<<<gridNH, BLK, 0, stream>>>(Y, accb, degset + (size_t)p * NN,
                                              fb + p * HH, dmat,
                                              hbias + p * HH, p, (p == 0) ? 1 : 0, outb);
        }
    };
    auto gnorm = [&](float* X, const float* w, const float* b, const float* ms){
        k_stats<<<GG, 1024, 0, stream>>>(X, gstart, sums, sumsq);
        k_gnorm<<<gridNH, BLK, 0, stream>>>(X, batch, gstart, sums, sumsq, w, b, ms);
    };

    for (int i = 0; i < LL; ++i){
        opdmp(xbuf, hbuf, uei, uew, deg,
              S_lin_W + (size_t)i * HH * HH, S_lin_b + (size_t)i * HH,
              S_d + (size_t)i * PP * HH, S_hb + (size_t)i * PP * HH,
              S_fW + (size_t)i * PP * 512 * HH, S_fb + (size_t)i * PP * HH);
        gnorm(hbuf, nS_w + (size_t)i * HH, nS_b + (size_t)i * HH, nS_m + (size_t)i * HH);
        opdmp(hbuf, fxbuf, fei, few, deg + (size_t)PP * NN,
              F_lin_W + (size_t)i * HH * HH, F_lin_b + (size_t)i * HH,
              F_d + (size_t)i * PP * HH, F_hb + (size_t)i * PP * HH,
              F_fW + (size_t)i * PP * 512 * HH, F_fb + (size_t)i * PP * HH);
        gnorm(fxbuf, nF_w + (size_t)i * HH, nF_b + (size_t)i * HH, nF_m + (size_t)i * HH);
        k_gate2<<<gridN64, BLK, 0, stream>>>(hbuf, fxbuf, gate_W, gate_b, xbuf);
    }

    k_stats<<<GG, 1024, 0, stream>>>(xbuf, gstart, sums, sumsq);
    k_finalout<<<(GG * HH + BLK - 1) / BLK, BLK, 0, stream>>>(sums, gstart, out);
}

// Round 4
// 2184.845 us; speedup vs baseline: 2.7215x; 1.1313x over previous
//
#include <hip/hip_runtime.h>
#include <cstdint>
#include <cstddef>

#define NN 50000
#define EE 300000
#define HH 64
#define PP 3
#define GG 50
#define LL 2
#define SLOPE 0.01f

__device__ __forceinline__ float lrelu(float x){ return x >= 0.f ? x : SLOPE*x; }

// gstart[g] = first index i with batch[i] >= g (batch sorted); gstart[GG] = NN
__global__ void k_bounds(const int* __restrict__ batch, int* __restrict__ gstart){
    int g = threadIdx.x;
    if (g > GG) return;
    int lo = 0, hi = NN;
    while (lo < hi){ int mid = (lo + hi) >> 1; if (batch[mid] < g) lo = mid + 1; else hi = mid; }
    gstart[g] = lo;
}

// deg[which][n] = sum of w over edges with row==n; which in 0..5 (u hops 0..2, f hops 0..2)
__global__ void k_deg(const int* __restrict__ uei, const float* __restrict__ uew,
                      const int* __restrict__ fei, const float* __restrict__ few,
                      float* __restrict__ deg){
    int t = blockIdx.x * blockDim.x + threadIdx.x;
    if (t >= 2 * PP * EE) return;
    int which = t / EE;
    int e = t - which * EE;
    const int* ei; const float* ew; int p;
    if (which < PP){ ei = uei; ew = uew; p = which; }
    else           { ei = fei; ew = few; p = which - PP; }
    int row = ei[(size_t)(p * 2 + 0) * EE + e];
    atomicAdd(deg + (size_t)which * NN + row, ew[(size_t)p * EE + e]);
}

// Register-blocked (N,64)@(64,64): 32 nodes/block, 4 waves, 8 nodes/wave, lane owns 1 column.
__global__ __launch_bounds__(256) void k_lin64(const float* __restrict__ X,
                       const float* __restrict__ W, const float* __restrict__ b,
                       float* __restrict__ out){
    __shared__ float xs[32][HH];
    int nb = blockIdx.x * 32;
    int t = threadIdx.x;
    #pragma unroll
    for (int i = 0; i < 2; ++i){
        int idx = t + 256 * i;
        int r = idx >> 4, c4 = idx & 15;
        int n = nb + r;
        float4 v = make_float4(0.f, 0.f, 0.f, 0.f);
        if (n < NN) v = *reinterpret_cast<const float4*>(X + (size_t)n * HH + c4 * 4);
        *reinterpret_cast<float4*>(&xs[r][c4 * 4]) = v;
    }
    __syncthreads();
    int lane = t & 63, wave = t >> 6, nw = wave * 8;
    float acc[8];
    float bb = b[lane];
    #pragma unroll
    for (int i = 0; i < 8; ++i) acc[i] = bb;
    #pragma unroll 2
    for (int k = 0; k < HH; ++k){
        float wv = W[(size_t)k * HH + lane];
        #pragma unroll
        for (int i = 0; i < 8; ++i) acc[i] += xs[nw + i][k] * wv;
    }
    #pragma unroll
    for (int i = 0; i < 8; ++i){
        int n = nb + nw + i;
        if (n < NN) out[(size_t)n * HH + lane] = acc[i];
    }
}

// Y[n, s, o], s in 0..7 (6 directional, avg, self), register-blocked GEMM.
// 32 nodes/block; each wave: 8 nodes; lane owns column `lane` of all 8 slices -> acc[8][8].
__global__ __launch_bounds__(256) void k_ybuild2(const float* __restrict__ xt,
                        const float* __restrict__ fW, float* __restrict__ Y){
    __shared__ float xs[32][HH];
    int nb = blockIdx.x * 32;
    int t = threadIdx.x;
    #pragma unroll
    for (int i = 0; i < 2; ++i){
        int idx = t + 256 * i;
        int r = idx >> 4, c4 = idx & 15;
        int n = nb + r;
        float4 v = make_float4(0.f, 0.f, 0.f, 0.f);
        if (n < NN) v = *reinterpret_cast<const float4*>(xt + (size_t)n * HH + c4 * 4);
        *reinterpret_cast<float4*>(&xs[r][c4 * 4]) = v;
    }
    __syncthreads();
    int lane = t & 63, wave = t >> 6, nw = wave * 8;
    float acc[8][8];
    #pragma unroll
    for (int i = 0; i < 8; ++i)
        #pragma unroll
        for (int j = 0; j < 8; ++j) acc[i][j] = 0.f;
    #pragma unroll 2
    for (int k = 0; k < HH; ++k){
        float wv[8];
        #pragma unroll
        for (int j = 0; j < 6; ++j) wv[j] = fW[(size_t)(128 + k * 6 + j) * HH + lane];
        wv[6] = fW[(size_t)(64 + k) * HH + lane];
        wv[7] = fW[(size_t)k * HH + lane];
        #pragma unroll
        for (int i = 0; i < 8; ++i){
            float xv = xs[nw + i][k];
            #pragma unroll
            for (int j = 0; j < 8; ++j) acc[i][j] += xv * wv[j];
        }
    }
    #pragma unroll
    for (int i = 0; i < 8; ++i){
        int n = nb + nw + i;
        if (n < NN){
            float* yr = Y + (size_t)n * 512 + lane;
            #pragma unroll
            for (int j = 0; j < 8; ++j) yr[j * 64] = acc[i][j];
        }
    }
}

// per edge: msg[o] = w*Y[col,6,o] + sum_d |diff_d| * Y[col, d + 3*(diff_d<0), o]; atomic into acc[row]
__global__ void k_edge(const int* __restrict__ rowi, const int* __restrict__ coli,
                       const float* __restrict__ w, const float* __restrict__ pe,
                       const float* __restrict__ Y, float* __restrict__ acc){
    int gid = blockIdx.x * blockDim.x + threadIdx.x;
    if (gid >= EE * HH) return;
    int e = gid >> 6, o = gid & 63;
    int row = rowi[e], col = coli[e];
    float we = w[e];
    float dr0 = pe[col * 3 + 0] - pe[row * 3 + 0];
    float dr1 = pe[col * 3 + 1] - pe[row * 3 + 1];
    float dr2 = pe[col * 3 + 2] - pe[row * 3 + 2];
    const float* Yc = Y + (size_t)col * 512;
    float m = we * Yc[6 * 64 + o];
    int s0 = (dr0 < 0.f) ? 3 : 0; m += fabsf(dr0) * Yc[s0 * 64 + o];
    int s1 = (dr1 < 0.f) ? 4 : 1; m += fabsf(dr1) * Yc[s1 * 64 + o];
    int s2 = (dr2 < 0.f) ? 5 : 2; m += fabsf(dr2) * Yc[s2 * 64 + o];
    atomicAdd(acc + (size_t)row * 64 + o, m);
}

// hop finalize: h_p = lrelu(Y[n,7,o] + deg_inv*acc + fb); out (+)= h_p * softmax_p(d)[p,o] + hb[o]
__global__ void k_fin(const float* __restrict__ Y, const float* __restrict__ acc,
                      const float* __restrict__ deg, const float* __restrict__ fb,
                      const float* __restrict__ dmat, const float* __restrict__ hb,
                      int p, int first, float* __restrict__ out){
    int gid = blockIdx.x * blockDim.x + threadIdx.x;
    if (gid >= NN * HH) return;
    int n = gid >> 6, o = gid & 63;
    float dg = deg[n];
    float di = (dg == 0.f) ? 0.f : 1.f / dg;
    float hpre = Y[(size_t)n * 512 + 448 + o] + di * acc[gid] + fb[o];
    float hp = lrelu(hpre);
    float d0 = dmat[0 * HH + o], d1 = dmat[1 * HH + o], d2 = dmat[2 * HH + o];
    float mx = fmaxf(d0, fmaxf(d1, d2));
    float e0 = expf(d0 - mx), e1 = expf(d1 - mx), e2 = expf(d2 - mx);
    float dw = ((p == 0) ? e0 : (p == 1) ? e1 : e2) / (e0 + e1 + e2);
    float v = hp * dw + hb[o];
    out[gid] = first ? v : (out[gid] + v);
}

// per-graph column sums/sumsq via per-wave run-length segments + atomics.
// block = 256 threads = 4 waves; each wave owns 64 contiguous nodes; batch sorted.
__global__ void k_stats2(const float* __restrict__ X, const int* __restrict__ batch,
                         float* __restrict__ sums, float* __restrict__ sumsq){
    int wave = threadIdx.x >> 6, lane = threadIdx.x & 63;
    int n0 = (blockIdx.x * 4 + wave) * 64;
    if (n0 >= NN) return;
    int n1 = n0 + 64; if (n1 > NN) n1 = NN;
    float s = 0.f, q = 0.f;
    int gcur = batch[n0];
    for (int n = n0; n < n1; ++n){
        int g = batch[n];                    // wave-uniform broadcast
        if (g != gcur){
            atomicAdd(&sums[gcur * 64 + lane], s);
            atomicAdd(&sumsq[gcur * 64 + lane], q);
            s = 0.f; q = 0.f; gcur = g;
        }
        float v = X[(size_t)n * 64 + lane];
        s += v; q += v * v;
    }
    atomicAdd(&sums[gcur * 64 + lane], s);
    atomicAdd(&sumsq[gcur * 64 + lane], q);
}

// graph-norm + leaky_relu, in place.  var = E[x^2] - mean^2 * ms * (2 - ms)
__global__ void k_gnorm(float* __restrict__ X, const int* __restrict__ batch,
                        const int* __restrict__ gstart,
                        const float* __restrict__ sums, const float* __restrict__ sumsq,
                        const float* __restrict__ w, const float* __restrict__ b,
                        const float* __restrict__ ms){
    int gid = blockIdx.x * blockDim.x + threadIdx.x;
    if (gid >= NN * HH) return;
    int n = gid >> 6, o = gid & 63;
    int g = batch[n];
    float cnt = fmaxf((float)(gstart[g + 1] - gstart[g]), 1.f);
    float mean = sums[g * 64 + o] / cnt;
    float ex2 = sumsq[g * 64 + o] / cnt;
    float m = ms[o];
    float var = ex2 - mean * mean * m * (2.f - m);
    float v = (X[gid] - mean * m) * (1.f / sqrtf(var + 1e-5f)) * w[o] + b[o];
    X[gid] = lrelu(v);
}

// gate = sigmoid([h,fx] @ gate_W + gate_b); X = gate*h + (1-gate)*fx + X
// 32 nodes/block register-blocked.
__global__ __launch_bounds__(256) void k_gate2(const float* __restrict__ h,
                       const float* __restrict__ fx, const float* __restrict__ gW,
                       const float* __restrict__ gb, float* __restrict__ X){
    __shared__ float hs[32][HH];
    __shared__ float fs[32][HH];
    int nb = blockIdx.x * 32;
    int t = threadIdx.x;
    #pragma unroll
    for (int i = 0; i < 2; ++i){
        int idx = t + 256 * i;
        int r = idx >> 4, c4 = idx & 15;
        int n = nb + r;
        float4 vh = make_float4(0.f, 0.f, 0.f, 0.f);
        float4 vf = make_float4(0.f, 0.f, 0.f, 0.f);
        if (n < NN){
            vh = *reinterpret_cast<const float4*>(h  + (size_t)n * HH + c4 * 4);
            vf = *reinterpret_cast<const float4*>(fx + (size_t)n * HH + c4 * 4);
        }
        *reinterpret_cast<float4*>(&hs[r][c4 * 4]) = vh;
        *reinterpret_cast<float4*>(&fs[r][c4 * 4]) = vf;
    }
    __syncthreads();
    int lane = t & 63, wave = t >> 6, nw = wave * 8;
    float acc[8];
    float bb = gb[lane];
    #pragma unroll
    for (int i = 0; i < 8; ++i) acc[i] = bb;
    #pragma unroll 2
    for (int k = 0; k < HH; ++k){
        float w1 = gW[(size_t)k * HH + lane];
        float w2 = gW[(size_t)(64 + k) * HH + lane];
        #pragma unroll
        for (int i = 0; i < 8; ++i) acc[i] += hs[nw + i][k] * w1 + fs[nw + i][k] * w2;
    }
    #pragma unroll
    for (int i = 0; i < 8; ++i){
        int n = nb + nw + i;
        if (n < NN){
            float gt = 1.f / (1.f + expf(-acc[i]));
            float hv = hs[nw + i][lane];
            float fv = fs[nw + i][lane];
            size_t idx = (size_t)n * HH + lane;
            X[idx] = gt * hv + (1.f - gt) * fv + X[idx];
        }
    }
}

__global__ void k_finalout(const float* __restrict__ sums, const int* __restrict__ gstart,
                           float* __restrict__ out){
    int gid = blockIdx.x * blockDim.x + threadIdx.x;
    if (gid >= GG * HH) return;
    int g = gid >> 6;
    float cnt = fmaxf((float)(gstart[g + 1] - gstart[g]), 1.f);
    out[gid] = sums[gid] / cnt;
}

extern "C" void kernel_launch(void* const* d_in, const int* in_sizes, int n_in,
                              void* d_out, int out_size, void* d_ws, size_t ws_size,
                              hipStream_t stream) {
    const float* x_in   = (const float*)d_in[0];
    const float* pe     = (const float*)d_in[1];
    const int*   batch  = (const int*)d_in[2];
    const int*   uei    = (const int*)d_in[3];
    const float* uew    = (const float*)d_in[4];
    const int*   fei    = (const int*)d_in[5];
    const float* few    = (const float*)d_in[6];
    const float* emb_W  = (const float*)d_in[7];
    const float* emb_b  = (const float*)d_in[8];
    const float* S_lin_W= (const float*)d_in[9];
    const float* S_lin_b= (const float*)d_in[10];
    const float* S_d    = (const float*)d_in[11];
    const float* S_hb   = (const float*)d_in[12];
    const float* S_fW   = (const float*)d_in[13];
    const float* S_fb   = (const float*)d_in[14];
    const float* F_lin_W= (const float*)d_in[15];
    const float* F_lin_b= (const float*)d_in[16];
    const float* F_d    = (const float*)d_in[17];
    const float* F_hb   = (const float*)d_in[18];
    const float* F_fW   = (const float*)d_in[19];
    const float* F_fb   = (const float*)d_in[20];
    const float* nS_w   = (const float*)d_in[21];
    const float* nS_b   = (const float*)d_in[22];
    const float* nS_m   = (const float*)d_in[23];
    const float* nF_w   = (const float*)d_in[24];
    const float* nF_b   = (const float*)d_in[25];
    const float* nF_m   = (const float*)d_in[26];
    const float* gate_W = (const float*)d_in[27];
    const float* gate_b = (const float*)d_in[28];
    float* out = (float*)d_out;

    size_t off = 0;
    auto alloc = [&](size_t bytes)->void*{
        void* p = (char*)d_ws + off;
        off += (bytes + 255) & ~(size_t)255;
        return p;
    };
    float* xbuf  = (float*)alloc((size_t)NN * HH * 4);
    float* hbuf  = (float*)alloc((size_t)NN * HH * 4);
    float* fxbuf = (float*)alloc((size_t)NN * HH * 4);
    float* xt    = (float*)alloc((size_t)NN * HH * 4);
    float* accb  = (float*)alloc((size_t)NN * HH * 4);
    float* Y     = (float*)alloc((size_t)NN * 512 * 4);
    float* deg   = (float*)alloc((size_t)6 * NN * 4);
    int*   gstart= (int*)  alloc((GG + 1) * 4);
    float* sums  = (float*)alloc(GG * HH * 4);
    float* sumsq = (float*)alloc(GG * HH * 4);

    const int BLK = 256;
    const int gridNH = (NN * HH) / BLK;          // 12500
    const int gridE  = (EE * HH) / BLK;          // 75000
    const int gridN32 = (NN + 31) / 32;          // 1563
    const int gridStats = (NN + 255) / 256;      // 196

    k_bounds<<<1, 64, 0, stream>>>(batch, gstart);
    hipMemsetAsync(deg, 0, (size_t)6 * NN * 4, stream);
    k_deg<<<(2 * PP * EE + BLK - 1) / BLK, BLK, 0, stream>>>(uei, uew, fei, few, deg);
    k_lin64<<<gridN32, BLK, 0, stream>>>(x_in, emb_W, emb_b, xbuf);

    auto opdmp = [&](const float* xin, float* outb, const int* ei, const float* ew,
                     const float* degset, const float* linW, const float* linb,
                     const float* dmat, const float* hbias, const float* fW, const float* fb){
        k_lin64<<<gridN32, BLK, 0, stream>>>(xin, linW, linb, xt);
        for (int p = 0; p < PP; ++p){
            k_ybuild2<<<gridN32, BLK, 0, stream>>>(xt, fW + (size_t)p * 512 * HH, Y);
            hipMemsetAsync(accb, 0, (size_t)NN * HH * 4, stream);
            k_edge<<<gridE, BLK, 0, stream>>>(ei + (size_t)(p * 2 + 0) * EE,
                                              ei + (size_t)(p * 2 + 1) * EE,
                                              ew + (size_t)p * EE, pe, Y, accb);
            k_fin<<<gridNH, BLK, 0, stream>>>(Y, accb, degset + (size_t)p * NN,
                                              fb + p * HH, dmat,
                                              hbias + p * HH, p, (p == 0) ? 1 : 0, outb);
        }
    };
    auto gnorm = [&](float* X, const float* w, const float* b, const float* ms){
        hipMemsetAsync(sums, 0, GG * HH * 4, stream);
        hipMemsetAsync(sumsq, 0, GG * HH * 4, stream);
        k_stats2<<<gridStats, BLK, 0, stream>>>(X, batch, sums, sumsq);
        k_gnorm<<<gridNH, BLK, 0, stream>>>(X, batch, gstart, sums, sumsq, w, b, ms);
    };

    for (int i = 0; i < LL; ++i){
        opdmp(xbuf, hbuf, uei, uew, deg,
              S_lin_W + (size_t)i * HH * HH, S_lin_b + (size_t)i * HH,
              S_d + (size_t)i * PP * HH, S_hb + (size_t)i * PP * HH,
              S_fW + (size_t)i * PP * 512 * HH, S_fb + (size_t)i * PP * HH);
        gnorm(hbuf, nS_w + (size_t)i * HH, nS_b + (size_t)i * HH, nS_m + (size_t)i * HH);
        opdmp(hbuf, fxbuf, fei, few, deg + (size_t)PP * NN,
              F_lin_W + (size_t)i * HH * HH, F_lin_b + (size_t)i * HH,
              F_d + (size_t)i * PP * HH, F_hb + (size_t)i * PP * HH,
              F_fW + (size_t)i * PP * 512 * HH, F_fb + (size_t)i * PP * HH);
        gnorm(fxbuf, nF_w + (size_t)i * HH, nF_b + (size_t)i * HH, nF_m + (size_t)i * HH);
        k_gate2<<<gridN32, BLK, 0, stream>>>(hbuf, fxbuf, gate_W, gate_b, xbuf);
    }

    hipMemsetAsync(sums, 0, GG * HH * 4, stream);
    hipMemsetAsync(sumsq, 0, GG * HH * 4, stream);
    k_stats2<<<gridStats, BLK, 0, stream>>>(xbuf, batch, sums, sumsq);
    k_finalout<<<(GG * HH + BLK - 1) / BLK, BLK, 0, stream>>>(sums, gstart, out);
}

// Round 5
// 2159.880 us; speedup vs baseline: 2.7529x; 1.0116x over previous
//
#include <hip/hip_runtime.h>
#include <cstdint>
#include <cstddef>

#define NN 50000
#define EE 300000
#define HH 64
#define PP 3
#define GG 50
#define LL 2
#define SLOPE 0.01f

__device__ __forceinline__ float lrelu(float x){ return x >= 0.f ? x : SLOPE*x; }

// gstart[g] = first index i with batch[i] >= g (batch sorted); gstart[GG] = NN
__global__ void k_bounds(const int* __restrict__ batch, int* __restrict__ gstart){
    int g = threadIdx.x;
    if (g > GG) return;
    int lo = 0, hi = NN;
    while (lo < hi){ int mid = (lo + hi) >> 1; if (batch[mid] < g) lo = mid + 1; else hi = mid; }
    gstart[g] = lo;
}

// One pass over all 6 edge sets: per-row edge counts (int) + weighted degree (float).
__global__ void k_count(const int* __restrict__ uei, const float* __restrict__ uew,
                        const int* __restrict__ fei, const float* __restrict__ few,
                        int* __restrict__ cnt, float* __restrict__ deg){
    int t = blockIdx.x * blockDim.x + threadIdx.x;
    if (t >= 2 * PP * EE) return;
    int which = t / EE;
    int e = t - which * EE;
    const int* ei; const float* ew; int p;
    if (which < PP){ ei = uei; ew = uew; p = which; }
    else           { ei = fei; ew = few; p = which - PP; }
    int row = ei[(size_t)(p * 2 + 0) * EE + e];
    atomicAdd(cnt + (size_t)which * NN + row, 1);
    atomicAdd(deg + (size_t)which * NN + row, ew[(size_t)p * EE + e]);
}

// Exclusive scan of cnt -> rowptr (and cursor copy). 6 blocks (one per edge set), 1024 thr.
__global__ __launch_bounds__(1024) void k_scan(const int* __restrict__ cnt,
                        int* __restrict__ rowptr, int* __restrict__ cursor){
    int which = blockIdx.x;
    const int* c = cnt + (size_t)which * NN;
    int* rp = rowptr + (size_t)which * (NN + 1);
    int* cur = cursor + (size_t)which * NN;
    __shared__ int wsum[16];
    __shared__ int carry_sh;
    int lane = threadIdx.x & 63, wave = threadIdx.x >> 6;
    if (threadIdx.x == 0) carry_sh = 0;
    __syncthreads();
    for (int base = 0; base < NN; base += 1024){
        int i = base + threadIdx.x;
        int v = (i < NN) ? c[i] : 0;
        int s = v;
        #pragma unroll
        for (int off = 1; off < 64; off <<= 1){
            int t = __shfl_up(s, off, 64);
            if (lane >= off) s += t;
        }
        if (lane == 63) wsum[wave] = s;
        __syncthreads();
        if (wave == 0 && lane < 16){
            int ws = wsum[lane];
            #pragma unroll
            for (int off = 1; off < 16; off <<= 1){
                int t = __shfl_up(ws, off, 64);
                if (lane >= off) ws += t;
            }
            wsum[lane] = ws;
        }
        __syncthreads();
        int carry = carry_sh;
        int wexcl = (wave == 0) ? 0 : wsum[wave - 1];
        int excl = carry + wexcl + s - v;
        if (i < NN){ rp[i] = excl; cur[i] = excl; }
        __syncthreads();
        if (threadIdx.x == 1023) carry_sh = carry + wsum[15];
        __syncthreads();
    }
    if (threadIdx.x == 0) rp[NN] = carry_sh;
}

// Counting-sort edges into CSR slots: csr_col / csr_w per edge set.
__global__ void k_fill(const int* __restrict__ uei, const float* __restrict__ uew,
                       const int* __restrict__ fei, const float* __restrict__ few,
                       int* __restrict__ cursor, int* __restrict__ csr_col,
                       float* __restrict__ csr_w){
    int t = blockIdx.x * blockDim.x + threadIdx.x;
    if (t >= 2 * PP * EE) return;
    int which = t / EE;
    int e = t - which * EE;
    const int* ei; const float* ew; int p;
    if (which < PP){ ei = uei; ew = uew; p = which; }
    else           { ei = fei; ew = few; p = which - PP; }
    int row = ei[(size_t)(p * 2 + 0) * EE + e];
    int col = ei[(size_t)(p * 2 + 1) * EE + e];
    float w = ew[(size_t)p * EE + e];
    int slot = atomicAdd(cursor + (size_t)which * NN + row, 1);
    csr_col[(size_t)which * EE + slot] = col;
    csr_w  [(size_t)which * EE + slot] = w;
}

// Register-blocked (N,64)@(64,64): 32 nodes/block, 4 waves, 8 nodes/wave, lane owns 1 column.
__global__ __launch_bounds__(256) void k_lin64(const float* __restrict__ X,
                       const float* __restrict__ W, const float* __restrict__ b,
                       float* __restrict__ out){
    __shared__ float xs[32][HH];
    int nb = blockIdx.x * 32;
    int t = threadIdx.x;
    #pragma unroll
    for (int i = 0; i < 2; ++i){
        int idx = t + 256 * i;
        int r = idx >> 4, c4 = idx & 15;
        int n = nb + r;
        float4 v = make_float4(0.f, 0.f, 0.f, 0.f);
        if (n < NN) v = *reinterpret_cast<const float4*>(X + (size_t)n * HH + c4 * 4);
        *reinterpret_cast<float4*>(&xs[r][c4 * 4]) = v;
    }
    __syncthreads();
    int lane = t & 63, wave = t >> 6, nw = wave * 8;
    float acc[8];
    float bb = b[lane];
    #pragma unroll
    for (int i = 0; i < 8; ++i) acc[i] = bb;
    #pragma unroll 2
    for (int k = 0; k < HH; ++k){
        float wv = W[(size_t)k * HH + lane];
        #pragma unroll
        for (int i = 0; i < 8; ++i) acc[i] += xs[nw + i][k] * wv;
    }
    #pragma unroll
    for (int i = 0; i < 8; ++i){
        int n = nb + nw + i;
        if (n < NN) out[(size_t)n * HH + lane] = acc[i];
    }
}

// Y[n, s, o], s in 0..7 (6 directional, avg, self), register-blocked GEMM.
__global__ __launch_bounds__(256) void k_ybuild2(const float* __restrict__ xt,
                        const float* __restrict__ fW, float* __restrict__ Y){
    __shared__ float xs[32][HH];
    int nb = blockIdx.x * 32;
    int t = threadIdx.x;
    #pragma unroll
    for (int i = 0; i < 2; ++i){
        int idx = t + 256 * i;
        int r = idx >> 4, c4 = idx & 15;
        int n = nb + r;
        float4 v = make_float4(0.f, 0.f, 0.f, 0.f);
        if (n < NN) v = *reinterpret_cast<const float4*>(xt + (size_t)n * HH + c4 * 4);
        *reinterpret_cast<float4*>(&xs[r][c4 * 4]) = v;
    }
    __syncthreads();
    int lane = t & 63, wave = t >> 6, nw = wave * 8;
    float acc[8][8];
    #pragma unroll
    for (int i = 0; i < 8; ++i)
        #pragma unroll
        for (int j = 0; j < 8; ++j) acc[i][j] = 0.f;
    #pragma unroll 2
    for (int k = 0; k < HH; ++k){
        float wv[8];
        #pragma unroll
        for (int j = 0; j < 6; ++j) wv[j] = fW[(size_t)(128 + k * 6 + j) * HH + lane];
        wv[6] = fW[(size_t)(64 + k) * HH + lane];
        wv[7] = fW[(size_t)k * HH + lane];
        #pragma unroll
        for (int i = 0; i < 8; ++i){
            float xv = xs[nw + i][k];
            #pragma unroll
            for (int j = 0; j < 8; ++j) acc[i][j] += xv * wv[j];
        }
    }
    #pragma unroll
    for (int i = 0; i < 8; ++i){
        int n = nb + nw + i;
        if (n < NN){
            float* yr = Y + (size_t)n * 512 + lane;
            #pragma unroll
            for (int j = 0; j < 8; ++j) yr[j * 64] = acc[i][j];
        }
    }
}

// One wave per node: gather CSR edges, accumulate msg, fused finalize (no atomics).
__global__ __launch_bounds__(256) void k_row(const float* __restrict__ Y,
        const int* __restrict__ csr_col, const float* __restrict__ csr_w,
        const int* __restrict__ rowptr, const float* __restrict__ deg,
        const float* __restrict__ pe, const float* __restrict__ fb,
        const float* __restrict__ dmat, const float* __restrict__ hb,
        int p, int first, float* __restrict__ out){
    int wave = threadIdx.x >> 6, lane = threadIdx.x & 63;
    int n = blockIdx.x * 4 + wave;
    if (n >= NN) return;
    int e0 = rowptr[n], e1 = rowptr[n + 1];
    float pr0 = pe[n * 3 + 0], pr1 = pe[n * 3 + 1], pr2 = pe[n * 3 + 2];
    float acc = 0.f;
    for (int e = e0; e < e1; ++e){
        int col = csr_col[e];
        float w = csr_w[e];
        float dr0 = pe[col * 3 + 0] - pr0;
        float dr1 = pe[col * 3 + 1] - pr1;
        float dr2 = pe[col * 3 + 2] - pr2;
        const float* Yc = Y + (size_t)col * 512;
        float m = w * Yc[6 * 64 + lane];
        m += fabsf(dr0) * Yc[((dr0 < 0.f) ? 3 : 0) * 64 + lane];
        m += fabsf(dr1) * Yc[((dr1 < 0.f) ? 4 : 1) * 64 + lane];
        m += fabsf(dr2) * Yc[((dr2 < 0.f) ? 5 : 2) * 64 + lane];
        acc += m;
    }
    float dg = deg[n];
    float di = (dg == 0.f) ? 0.f : 1.f / dg;
    float hpre = Y[(size_t)n * 512 + 448 + lane] + di * acc + fb[lane];
    float hp = lrelu(hpre);
    float d0 = dmat[0 * HH + lane], d1 = dmat[1 * HH + lane], d2 = dmat[2 * HH + lane];
    float mx = fmaxf(d0, fmaxf(d1, d2));
    float e0f = expf(d0 - mx), e1f = expf(d1 - mx), e2f = expf(d2 - mx);
    float dw = ((p == 0) ? e0f : (p == 1) ? e1f : e2f) / (e0f + e1f + e2f);
    float v = hp * dw + hb[lane];
    size_t oidx = (size_t)n * HH + lane;
    out[oidx] = first ? v : (out[oidx] + v);
}

// per-graph column sums/sumsq via per-wave run-length segments + atomics.
__global__ void k_stats2(const float* __restrict__ X, const int* __restrict__ batch,
                         float* __restrict__ sums, float* __restrict__ sumsq){
    int wave = threadIdx.x >> 6, lane = threadIdx.x & 63;
    int n0 = (blockIdx.x * 4 + wave) * 64;
    if (n0 >= NN) return;
    int n1 = n0 + 64; if (n1 > NN) n1 = NN;
    float s = 0.f, q = 0.f;
    int gcur = batch[n0];
    for (int n = n0; n < n1; ++n){
        int g = batch[n];
        if (g != gcur){
            atomicAdd(&sums[gcur * 64 + lane], s);
            atomicAdd(&sumsq[gcur * 64 + lane], q);
            s = 0.f; q = 0.f; gcur = g;
        }
        float v = X[(size_t)n * 64 + lane];
        s += v; q += v * v;
    }
    atomicAdd(&sums[gcur * 64 + lane], s);
    atomicAdd(&sumsq[gcur * 64 + lane], q);
}

// graph-norm + leaky_relu, in place.  var = E[x^2] - mean^2 * ms * (2 - ms)
__global__ void k_gnorm(float* __restrict__ X, const int* __restrict__ batch,
                        const int* __restrict__ gstart,
                        const float* __restrict__ sums, const float* __restrict__ sumsq,
                        const float* __restrict__ w, const float* __restrict__ b,
                        const float* __restrict__ ms){
    int gid = blockIdx.x * blockDim.x + threadIdx.x;
    if (gid >= NN * HH) return;
    int n = gid >> 6, o = gid & 63;
    int g = batch[n];
    float cnt = fmaxf((float)(gstart[g + 1] - gstart[g]), 1.f);
    float mean = sums[g * 64 + o] / cnt;
    float ex2 = sumsq[g * 64 + o] / cnt;
    float m = ms[o];
    float var = ex2 - mean * mean * m * (2.f - m);
    float v = (X[gid] - mean * m) * (1.f / sqrtf(var + 1e-5f)) * w[o] + b[o];
    X[gid] = lrelu(v);
}

// gate = sigmoid([h,fx] @ gate_W + gate_b); X = gate*h + (1-gate)*fx + X
__global__ __launch_bounds__(256) void k_gate2(const float* __restrict__ h,
                       const float* __restrict__ fx, const float* __restrict__ gW,
                       const float* __restrict__ gb, float* __restrict__ X){
    __shared__ float hs[32][HH];
    __shared__ float fs[32][HH];
    int nb = blockIdx.x * 32;
    int t = threadIdx.x;
    #pragma unroll
    for (int i = 0; i < 2; ++i){
        int idx = t + 256 * i;
        int r = idx >> 4, c4 = idx & 15;
        int n = nb + r;
        float4 vh = make_float4(0.f, 0.f, 0.f, 0.f);
        float4 vf = make_float4(0.f, 0.f, 0.f, 0.f);
        if (n < NN){
            vh = *reinterpret_cast<const float4*>(h  + (size_t)n * HH + c4 * 4);
            vf = *reinterpret_cast<const float4*>(fx + (size_t)n * HH + c4 * 4);
        }
        *reinterpret_cast<float4*>(&hs[r][c4 * 4]) = vh;
        *reinterpret_cast<float4*>(&fs[r][c4 * 4]) = vf;
    }
    __syncthreads();
    int lane = t & 63, wave = t >> 6, nw = wave * 8;
    float acc[8];
    float bb = gb[lane];
    #pragma unroll
    for (int i = 0; i < 8; ++i) acc[i] = bb;
    #pragma unroll 2
    for (int k = 0; k < HH; ++k){
        float w1 = gW[(size_t)k * HH + lane];
        float w2 = gW[(size_t)(64 + k) * HH + lane];
        #pragma unroll
        for (int i = 0; i < 8; ++i) acc[i] += hs[nw + i][k] * w1 + fs[nw + i][k] * w2;
    }
    #pragma unroll
    for (int i = 0; i < 8; ++i){
        int n = nb + nw + i;
        if (n < NN){
            float gt = 1.f / (1.f + expf(-acc[i]));
            float hv = hs[nw + i][lane];
            float fv = fs[nw + i][lane];
            size_t idx = (size_t)n * HH + lane;
            X[idx] = gt * hv + (1.f - gt) * fv + X[idx];
        }
    }
}

__global__ void k_finalout(const float* __restrict__ sums, const int* __restrict__ gstart,
                           float* __restrict__ out){
    int gid = blockIdx.x * blockDim.x + threadIdx.x;
    if (gid >= GG * HH) return;
    int g = gid >> 6;
    float cnt = fmaxf((float)(gstart[g + 1] - gstart[g]), 1.f);
    out[gid] = sums[gid] / cnt;
}

extern "C" void kernel_launch(void* const* d_in, const int* in_sizes, int n_in,
                              void* d_out, int out_size, void* d_ws, size_t ws_size,
                              hipStream_t stream) {
    const float* x_in   = (const float*)d_in[0];
    const float* pe     = (const float*)d_in[1];
    const int*   batch  = (const int*)d_in[2];
    const int*   uei    = (const int*)d_in[3];
    const float* uew    = (const float*)d_in[4];
    const int*   fei    = (const int*)d_in[5];
    const float* few    = (const float*)d_in[6];
    const float* emb_W  = (const float*)d_in[7];
    const float* emb_b  = (const float*)d_in[8];
    const float* S_lin_W= (const float*)d_in[9];
    const float* S_lin_b= (const float*)d_in[10];
    const float* S_d    = (const float*)d_in[11];
    const float* S_hb   = (const float*)d_in[12];
    const float* S_fW   = (const float*)d_in[13];
    const float* S_fb   = (const float*)d_in[14];
    const float* F_lin_W= (const float*)d_in[15];
    const float* F_lin_b= (const float*)d_in[16];
    const float* F_d    = (const float*)d_in[17];
    const float* F_hb   = (const float*)d_in[18];
    const float* F_fW   = (const float*)d_in[19];
    const float* F_fb   = (const float*)d_in[20];
    const float* nS_w   = (const float*)d_in[21];
    const float* nS_b   = (const float*)d_in[22];
    const float* nS_m   = (const float*)d_in[23];
    const float* nF_w   = (const float*)d_in[24];
    const float* nF_b   = (const float*)d_in[25];
    const float* nF_m   = (const float*)d_in[26];
    const float* gate_W = (const float*)d_in[27];
    const float* gate_b = (const float*)d_in[28];
    float* out = (float*)d_out;

    size_t off = 0;
    auto alloc = [&](size_t bytes)->void*{
        void* p = (char*)d_ws + off;
        off += (bytes + 255) & ~(size_t)255;
        return p;
    };
    float* xbuf   = (float*)alloc((size_t)NN * HH * 4);
    float* hbuf   = (float*)alloc((size_t)NN * HH * 4);
    float* fxbuf  = (float*)alloc((size_t)NN * HH * 4);
    float* xt     = (float*)alloc((size_t)NN * HH * 4);
    float* Y      = (float*)alloc((size_t)NN * 512 * 4);
    float* deg    = (float*)alloc((size_t)6 * NN * 4);
    int*   cnt    = (int*)  alloc((size_t)6 * NN * 4);
    int*   rowptr = (int*)  alloc((size_t)6 * (NN + 1) * 4);
    int*   cursor = (int*)  alloc((size_t)6 * NN * 4);
    int*   csr_col= (int*)  alloc((size_t)6 * EE * 4);
    float* csr_w  = (float*)alloc((size_t)6 * EE * 4);
    int*   gstart = (int*)  alloc((GG + 1) * 4);
    float* sums   = (float*)alloc(GG * HH * 4);
    float* sumsq  = (float*)alloc(GG * HH * 4);

    const int BLK = 256;
    const int gridNH = (NN * HH) / BLK;          // 12500
    const int gridN32 = (NN + 31) / 32;          // 1563
    const int gridRow = (NN + 3) / 4;            // 12500
    const int gridStats = (NN + 255) / 256;      // 196
    const int gridEdges = (2 * PP * EE + BLK - 1) / BLK;

    k_bounds<<<1, 64, 0, stream>>>(batch, gstart);
    hipMemsetAsync(deg, 0, (size_t)6 * NN * 4, stream);
    hipMemsetAsync(cnt, 0, (size_t)6 * NN * 4, stream);
    k_count<<<gridEdges, BLK, 0, stream>>>(uei, uew, fei, few, cnt, deg);
    k_scan<<<6, 1024, 0, stream>>>(cnt, rowptr, cursor);
    k_fill<<<gridEdges, BLK, 0, stream>>>(uei, uew, fei, few, cursor, csr_col, csr_w);
    k_lin64<<<gridN32, BLK, 0, stream>>>(x_in, emb_W, emb_b, xbuf);

    // which: 0..2 = u-edge hops, 3..5 = f-edge hops
    auto opdmp = [&](const float* xin, float* outb, int whichBase,
                     const float* linW, const float* linb,
                     const float* dmat, const float* hbias, const float* fW, const float* fb){
        k_lin64<<<gridN32, BLK, 0, stream>>>(xin, linW, linb, xt);
        for (int p = 0; p < PP; ++p){
            int which = whichBase + p;
            k_ybuild2<<<gridN32, BLK, 0, stream>>>(xt, fW + (size_t)p * 512 * HH, Y);
            k_row<<<gridRow, BLK, 0, stream>>>(Y,
                    csr_col + (size_t)which * EE, csr_w + (size_t)which * EE,
                    rowptr + (size_t)which * (NN + 1), deg + (size_t)which * NN,
                    pe, fb + p * HH, dmat, hbias + p * HH, p, (p == 0) ? 1 : 0, outb);
        }
    };
    auto gnorm = [&](float* X, const float* w, const float* b, const float* ms){
        hipMemsetAsync(sums, 0, GG * HH * 4, stream);
        hipMemsetAsync(sumsq, 0, GG * HH * 4, stream);
        k_stats2<<<gridStats, BLK, 0, stream>>>(X, batch, sums, sumsq);
        k_gnorm<<<gridNH, BLK, 0, stream>>>(X, batch, gstart, sums, sumsq, w, b, ms);
    };

    for (int i = 0; i < LL; ++i){
        opdmp(xbuf, hbuf, 0,
              S_lin_W + (size_t)i * HH * HH, S_lin_b + (size_t)i * HH,
              S_d + (size_t)i * PP * HH, S_hb + (size_t)i * PP * HH,
              S_fW + (size_t)i * PP * 512 * HH, S_fb + (size_t)i * PP * HH);
        gnorm(hbuf, nS_w + (size_t)i * HH, nS_b + (size_t)i * HH, nS_m + (size_t)i * HH);
        opdmp(hbuf, fxbuf, PP,
              F_lin_W + (size_t)i * HH * HH, F_lin_b + (size_t)i * HH,
              F_d + (size_t)i * PP * HH, F_hb + (size_t)i * PP * HH,
              F_fW + (size_t)i * PP * 512 * HH, F_fb + (size_t)i * PP * HH);
        gnorm(fxbuf, nF_w + (size_t)i * HH, nF_b + (size_t)i * HH, nF_m + (size_t)i * HH);
        k_gate2<<<gridN32, BLK, 0, stream>>>(hbuf, fxbuf, gate_W, gate_b, xbuf);
    }

    hipMemsetAsync(sums, 0, GG * HH * 4, stream);
    hipMemsetAsync(sumsq, 0, GG * HH * 4, stream);
    k_stats2<<<gridStats, BLK, 0, stream>>>(xbuf, batch, sums, sumsq);
    k_finalout<<<(GG * HH + BLK - 1) / BLK, BLK, 0, stream>>>(sums, gstart, out);
}